// Round 4
// baseline (158.355 us; speedup 1.0000x reference)
//
#include <hip/hip_runtime.h>
#include <math.h>

#define BATCH 8192
#define WALK  91      // L + 1 + L_NS = 80 + 1 + 10
#define LVAL  80
#define DIM   128
#define ROWS_PER_BLOCK 4
#define NBLOCKS (BATCH / ROWS_PER_BLOCK)   // 2048

// One wave (64 lanes) per batch row.
// 16 lanes per walk entry (8 dims each, 2x float4); wave covers 4 entries/iter.
// Final mean fused via last-block-done: the block that finishes last reduces
// all 8192 row losses in FIXED order -> bit-deterministic result.
__global__ __launch_bounds__(256, 8)
void node2vec_loss_kernel(const float* __restrict__ X,
                          const int* __restrict__ rw,   // int32 indices (JAX x64 off)
                          float* __restrict__ row_loss,
                          unsigned int* __restrict__ counter,
                          float* __restrict__ out) {
    __shared__ int s_idx[ROWS_PER_BLOCK * WALK];
    __shared__ bool s_last;

    const int wave = threadIdx.x >> 6;
    const int lane = threadIdx.x & 63;
    const int grp  = lane >> 4;       // 0..3: which walk entry in the quad
    const int sub  = lane & 15;       // 0..15: which 8-dim slice
    const int row_base = blockIdx.x * ROWS_PER_BLOCK;

    // Cooperative, coalesced load of the 4 rows' walk indices into LDS.
    for (int i = threadIdx.x; i < ROWS_PER_BLOCK * WALK; i += 256) {
        s_idx[i] = rw[row_base * WALK + i];
    }
    __syncthreads();

    const int* my_idx = s_idx + wave * WALK;
    const int b = row_base + wave;

    // Start-node fragment: dims [sub*8, sub*8+8) in registers.
    const size_t idx0 = (size_t)my_idx[0];
    const float4 xs0 = *(const float4*)(X + idx0 * DIM + sub * 8);
    const float4 xs1 = *(const float4*)(X + idx0 * DIM + sub * 8 + 4);

    float sumexp = 0.0f;   // per-lane: sum over this group's k's
    float num    = 0.0f;

    // 23 quads cover k = 0..91; k == 91 is masked out.
    #pragma unroll 4
    for (int i = 0; i < 23; ++i) {
        const int k = i * 4 + grp;
        const int kc = (k < WALK) ? k : 0;          // safe index for the pad slot
        const size_t idx = (size_t)my_idx[kc];
        const float4* base = (const float4*)(X + idx * DIM + sub * 8);
        const float4 a = base[0];
        const float4 c = base[1];

        float p = a.x * xs0.x + a.y * xs0.y + a.z * xs0.z + a.w * xs0.w
                + c.x * xs1.x + c.y * xs1.y + c.z * xs1.z + c.w * xs1.w;
        // Reduce over the 16 lanes of this group (xor bits 0..3 stay in-group).
        p += __shfl_xor(p, 1);
        p += __shfl_xor(p, 2);
        p += __shfl_xor(p, 4);
        p += __shfl_xor(p, 8);

        if (k < WALK) {
            sumexp += __expf(p);
            if (k >= 1 && k <= LVAL) num += p;
        }
    }

    // Combine the 4 groups' partial sums across the wave.
    sumexp += __shfl_xor(sumexp, 16);
    sumexp += __shfl_xor(sumexp, 32);
    num    += __shfl_xor(num, 16);
    num    += __shfl_xor(num, 32);

    if (lane == 0) {
        const float loss = (float)LVAL * __logf(sumexp) - num;
        // Agent-scope store: visible device-wide (cross-XCD) to the last block.
        __hip_atomic_store(row_loss + b, loss, __ATOMIC_RELAXED,
                           __HIP_MEMORY_SCOPE_AGENT);
    }

    // ---- last-block-done fused mean ----
    __syncthreads();   // drains this block's stores (vmcnt(0) before barrier)
    if (threadIdx.x == 0) {
        unsigned int prev = __hip_atomic_fetch_add(counter, 1u, __ATOMIC_ACQ_REL,
                                                   __HIP_MEMORY_SCOPE_AGENT);
        s_last = (prev == NBLOCKS - 1);
    }
    __syncthreads();

    if (s_last) {
        __shared__ double sdata[256];
        double acc = 0.0;
        for (int i = threadIdx.x; i < BATCH; i += 256) {
            acc += (double)__hip_atomic_load(row_loss + i, __ATOMIC_RELAXED,
                                             __HIP_MEMORY_SCOPE_AGENT);
        }
        sdata[threadIdx.x] = acc;
        __syncthreads();
        for (int s = 128; s > 0; s >>= 1) {
            if ((int)threadIdx.x < s) sdata[threadIdx.x] += sdata[threadIdx.x + s];
            __syncthreads();
        }
        if (threadIdx.x == 0) {
            out[0] = (float)(sdata[0] / (double)BATCH);
        }
    }
}

extern "C" void kernel_launch(void* const* d_in, const int* in_sizes, int n_in,
                              void* d_out, int out_size, void* d_ws, size_t ws_size,
                              hipStream_t stream) {
    const float* X = (const float*)d_in[0];
    const int* rw = (const int*)d_in[1];
    // d_in[2] is l == 80, a compile-time constant here (LVAL).
    float* row_loss = (float*)d_ws;                     // 8192 floats
    unsigned int* counter = (unsigned int*)((char*)d_ws + BATCH * sizeof(float));
    float* out = (float*)d_out;

    // Reset the completion counter every call (d_ws is NOT re-poisoned between
    // replays; memset is graph-capturable).
    hipMemsetAsync(counter, 0, sizeof(unsigned int), stream);

    node2vec_loss_kernel<<<NBLOCKS, 256, 0, stream>>>(X, rw, row_loss, counter, out);
}

// Round 5
// 83.551 us; speedup vs baseline: 1.8953x; 1.8953x over previous
//
#include <hip/hip_runtime.h>
#include <math.h>

#define BATCH 8192
#define WALK  91      // L + 1 + L_NS = 80 + 1 + 10
#define LVAL  80
#define DIM   128
#define ROWS_PER_BLOCK 4
#define NBLOCKS (BATCH / ROWS_PER_BLOCK)   // 2048
#define FIX_SCALE 1048576.0                // 2^20 fixed-point for deterministic sum

// One wave (64 lanes) per batch row.
// 16 lanes per walk entry (8 dims each, 2x float4); wave covers 4 entries/iter.
// Mean fused via int64 fixed-point atomics (associative -> deterministic) and
// a fence-free last-block-done: relaxed agent atomics only (they operate at
// the coherent LLC point), manual s_waitcnt for ordering. NO acq/rel fences —
// on multi-XCD gfx950 those emit buffer_wbl2/buffer_inv L2 flushes (R4: 2.2x).
__global__ __launch_bounds__(256, 8)
void node2vec_loss_kernel(const float* __restrict__ X,
                          const int* __restrict__ rw,   // int32 indices (JAX x64 off)
                          long long* __restrict__ accum,
                          unsigned int* __restrict__ counter,
                          float* __restrict__ out) {
    __shared__ int s_idx[ROWS_PER_BLOCK * WALK];
    __shared__ float s_loss[ROWS_PER_BLOCK];
    __shared__ bool s_last;

    const int wave = threadIdx.x >> 6;
    const int lane = threadIdx.x & 63;
    const int grp  = lane >> 4;       // 0..3: which walk entry in the quad
    const int sub  = lane & 15;       // 0..15: which 8-dim slice
    const int row_base = blockIdx.x * ROWS_PER_BLOCK;

    // Cooperative, coalesced load of the 4 rows' walk indices into LDS.
    for (int i = threadIdx.x; i < ROWS_PER_BLOCK * WALK; i += 256) {
        s_idx[i] = rw[row_base * WALK + i];
    }
    __syncthreads();

    const int* my_idx = s_idx + wave * WALK;

    // Start-node fragment: dims [sub*8, sub*8+8) in registers.
    const size_t idx0 = (size_t)my_idx[0];
    const float4 xs0 = *(const float4*)(X + idx0 * DIM + sub * 8);
    const float4 xs1 = *(const float4*)(X + idx0 * DIM + sub * 8 + 4);

    float sumexp = 0.0f;   // per-lane: sum over this group's k's
    float num    = 0.0f;

    // 23 quads cover k = 0..91; k == 91 is masked out.
    #pragma unroll 4
    for (int i = 0; i < 23; ++i) {
        const int k = i * 4 + grp;
        const int kc = (k < WALK) ? k : 0;          // safe index for the pad slot
        const size_t idx = (size_t)my_idx[kc];
        const float4* base = (const float4*)(X + idx * DIM + sub * 8);
        const float4 a = base[0];
        const float4 c = base[1];

        float p = a.x * xs0.x + a.y * xs0.y + a.z * xs0.z + a.w * xs0.w
                + c.x * xs1.x + c.y * xs1.y + c.z * xs1.z + c.w * xs1.w;
        // Reduce over the 16 lanes of this group (xor bits 0..3 stay in-group).
        p += __shfl_xor(p, 1);
        p += __shfl_xor(p, 2);
        p += __shfl_xor(p, 4);
        p += __shfl_xor(p, 8);

        if (k < WALK) {
            sumexp += __expf(p);
            if (k >= 1 && k <= LVAL) num += p;
        }
    }

    // Combine the 4 groups' partial sums across the wave.
    sumexp += __shfl_xor(sumexp, 16);
    sumexp += __shfl_xor(sumexp, 32);
    num    += __shfl_xor(num, 16);
    num    += __shfl_xor(num, 32);

    if (lane == 0) {
        s_loss[wave] = (float)LVAL * __logf(sumexp) - num;
    }
    __syncthreads();

    if (threadIdx.x == 0) {
        // Fixed-order block combine (deterministic), then one int64 atomic.
        double block_sum = 0.0;
        #pragma unroll
        for (int w = 0; w < ROWS_PER_BLOCK; ++w) block_sum += (double)s_loss[w];
        const long long add = __double2ll_rn(block_sum * FIX_SCALE);

        // Returning atomic (sc0): vmcnt tracks completion at the coherent LLC.
        long long old = __hip_atomic_fetch_add(accum, add, __ATOMIC_RELAXED,
                                               __HIP_MEMORY_SCOPE_AGENT);
        asm volatile("" :: "v"(old));                    // keep the return live
        asm volatile("s_waitcnt vmcnt(0)" ::: "memory"); // accum-add done BEFORE counter++
        unsigned int prev = __hip_atomic_fetch_add(counter, 1u, __ATOMIC_RELAXED,
                                                   __HIP_MEMORY_SCOPE_AGENT);
        s_last = (prev == NBLOCKS - 1);
    }
    __syncthreads();

    if (s_last && threadIdx.x == 0) {
        // All 2048 accum-adds completed at the LLC before their counter++ became
        // visible; relaxed agent load bypasses the (possibly stale) local L2.
        long long total = __hip_atomic_load(accum, __ATOMIC_RELAXED,
                                            __HIP_MEMORY_SCOPE_AGENT);
        out[0] = (float)(((double)total / FIX_SCALE) / (double)BATCH);
    }
}

extern "C" void kernel_launch(void* const* d_in, const int* in_sizes, int n_in,
                              void* d_out, int out_size, void* d_ws, size_t ws_size,
                              hipStream_t stream) {
    const float* X = (const float*)d_in[0];
    const int* rw = (const int*)d_in[1];
    // d_in[2] is l == 80, a compile-time constant here (LVAL).
    long long* accum = (long long*)d_ws;                       // 8 bytes
    unsigned int* counter = (unsigned int*)((char*)d_ws + 8);  // 4 bytes
    float* out = (float*)d_out;

    // Zero accumulator + counter every call (graph-capturable memset node).
    hipMemsetAsync(d_ws, 0, 16, stream);

    node2vec_loss_kernel<<<NBLOCKS, 256, 0, stream>>>(X, rw, accum, counter, out);
}

// Round 6
// 64.553 us; speedup vs baseline: 2.4531x; 1.2943x over previous
//
#include <hip/hip_runtime.h>
#include <math.h>

#define BATCH 8192
#define WALK  91      // L + 1 + L_NS = 80 + 1 + 10
#define LVAL  80
#define DIM   128
#define ROWS_PER_BLOCK 4

// One wave (64 lanes) per batch row.
// 16 lanes per walk entry (8 dims each, 2x float4); wave covers 4 entries/iter.
// R4/R5 lesson: do NOT fuse the final mean — cross-XCD acq/rel fences flush L2
// (2.2x regression), and even fence-free fusion + memset node costs ~12 us more
// than a plain second dispatch. Two kernels, no atomics, no workspace memset.
__global__ __launch_bounds__(256, 8)
void node2vec_loss_kernel(const float* __restrict__ X,
                          const int* __restrict__ rw,   // int32 indices (JAX x64 off)
                          float* __restrict__ row_loss) {
    __shared__ int s_idx[ROWS_PER_BLOCK * WALK];

    const int wave = threadIdx.x >> 6;
    const int lane = threadIdx.x & 63;
    const int grp  = lane >> 4;       // 0..3: which walk entry in the quad
    const int sub  = lane & 15;       // 0..15: which 8-dim slice
    const int row_base = blockIdx.x * ROWS_PER_BLOCK;

    // Cooperative, coalesced load of the 4 rows' walk indices into LDS.
    for (int i = threadIdx.x; i < ROWS_PER_BLOCK * WALK; i += 256) {
        s_idx[i] = rw[row_base * WALK + i];
    }
    __syncthreads();

    const int* my_idx = s_idx + wave * WALK;
    const int b = row_base + wave;

    // Start-node fragment: dims [sub*8, sub*8+8) in registers.
    const size_t idx0 = (size_t)my_idx[0];
    const float4 xs0 = *(const float4*)(X + idx0 * DIM + sub * 8);
    const float4 xs1 = *(const float4*)(X + idx0 * DIM + sub * 8 + 4);

    float sumexp = 0.0f;   // per-lane: sum over this group's k's
    float num    = 0.0f;

    // 23 quads cover k = 0..91; k == 91 is masked out.
    #pragma unroll 4
    for (int i = 0; i < 23; ++i) {
        const int k = i * 4 + grp;
        const int kc = (k < WALK) ? k : 0;          // safe index for the pad slot
        const size_t idx = (size_t)my_idx[kc];
        const float4* base = (const float4*)(X + idx * DIM + sub * 8);
        const float4 a = base[0];
        const float4 c = base[1];

        float p = a.x * xs0.x + a.y * xs0.y + a.z * xs0.z + a.w * xs0.w
                + c.x * xs1.x + c.y * xs1.y + c.z * xs1.z + c.w * xs1.w;
        // Reduce over the 16 lanes of this group (xor bits 0..3 stay in-group).
        p += __shfl_xor(p, 1);
        p += __shfl_xor(p, 2);
        p += __shfl_xor(p, 4);
        p += __shfl_xor(p, 8);

        if (k < WALK) {
            sumexp += __expf(p);
            if (k >= 1 && k <= LVAL) num += p;
        }
    }

    // Combine the 4 groups' partial sums across the wave.
    sumexp += __shfl_xor(sumexp, 16);
    sumexp += __shfl_xor(sumexp, 32);
    num    += __shfl_xor(num, 16);
    num    += __shfl_xor(num, 32);

    if (lane == 0) {
        row_loss[b] = (float)LVAL * __logf(sumexp) - num;
    }
}

// Deterministic single-block mean over the 8192 per-row losses.
// 512 threads x float4: each thread reads 4 contiguous floats, 4 strided iters.
__global__ __launch_bounds__(512)
void reduce_mean_kernel(const float* __restrict__ row_loss,
                        float* __restrict__ out) {
    __shared__ double sdata[512];
    double acc = 0.0;
    for (int i = threadIdx.x; i < BATCH / 4; i += 512) {
        const float4 v = ((const float4*)row_loss)[i];
        acc += ((double)v.x + (double)v.y) + ((double)v.z + (double)v.w);
    }
    sdata[threadIdx.x] = acc;
    __syncthreads();
    for (int s = 256; s > 0; s >>= 1) {
        if ((int)threadIdx.x < s) sdata[threadIdx.x] += sdata[threadIdx.x + s];
        __syncthreads();
    }
    if (threadIdx.x == 0) {
        out[0] = (float)(sdata[0] / (double)BATCH);
    }
}

extern "C" void kernel_launch(void* const* d_in, const int* in_sizes, int n_in,
                              void* d_out, int out_size, void* d_ws, size_t ws_size,
                              hipStream_t stream) {
    const float* X = (const float*)d_in[0];
    const int* rw = (const int*)d_in[1];
    // d_in[2] is l == 80, a compile-time constant here (LVAL).
    float* row_loss = (float*)d_ws;   // 8192 floats = 32 KB scratch
    float* out = (float*)d_out;

    node2vec_loss_kernel<<<BATCH / ROWS_PER_BLOCK, 256, 0, stream>>>(X, rw, row_loss);
    reduce_mean_kernel<<<1, 512, 0, stream>>>(row_loss, out);
}